// Round 4
// baseline (436.116 us; speedup 1.0000x reference)
//
#include <hip/hip_runtime.h>
#include <math.h>

#define B_  8
#define T_  8192
#define T2_ 4096
#define F_  512
#define F4_ 128
#define K_  8

typedef unsigned long long u64;
typedef float fvec4 __attribute__((ext_vector_type(4)));

// Sorted-descending top-8 insert of packed key (abs_bits<<32)|~t2.
// Keys unique (t2 unique); ~t2 gives lower-index-first on equal abs,
// matching jax.lax.top_k.
__device__ __forceinline__ void ins8(u64 (&a)[K_], u64 k) {
    if (k <= a[K_ - 1]) return;
#pragma unroll
    for (int j = 0; j < K_; ++j) {
        u64 hi = (k > a[j]) ? k : a[j];
        u64 lo = (k > a[j]) ? a[j] : k;
        a[j] = hi;
        k = lo;
    }
}

// Phase 1: stream x once (float4 lanes over f). Write main twice-interleaved,
// zero-fill detail, emit per-(col,slot) top-8 candidate keys.
// Unrolled x2 with loads hoisted: 4 KB/wave in flight -> latency hiding.
__global__ __launch_bounds__(256) void haar_phase1(
    const fvec4* __restrict__ x4, fvec4* __restrict__ out4,
    u64* __restrict__ cand, int S, int L)
{
    const int tx   = threadIdx.x;
    const int f4   = blockIdx.x * 64 + tx;            // 0..127
    const int slot = blockIdx.y * 4 + threadIdx.y;    // 0..S-1
    const int b    = blockIdx.z;
    const int t2_0 = slot * L;

    u64 a0[K_], a1[K_], a2[K_], a3[K_];
#pragma unroll
    for (int j = 0; j < K_; ++j) { a0[j] = 0; a1[j] = 0; a2[j] = 0; a3[j] = 0; }

    fvec4* mainOut = out4;
    fvec4* detOut  = out4 + (size_t)B_ * T_ * F4_;
    const size_t rowBase = (size_t)b * T_;
    const fvec4 z = {0.f, 0.f, 0.f, 0.f};

    for (int t = 0; t < L; t += 2) {
        const int t2a = t2_0 + t;
        const size_t ra = (rowBase + 2 * (size_t)t2a) * F4_ + f4;
        const size_t rb = ra + 2 * F4_;
        fvec4 e0 = x4[ra];
        fvec4 o0 = x4[ra + F4_];
        fvec4 e1 = x4[rb];
        fvec4 o1 = x4[rb + F4_];
        fvec4 low0 = (e0 + o0) * 0.5f;
        fvec4 low1 = (e1 + o1) * 0.5f;
        mainOut[ra]        = low0;
        mainOut[ra + F4_]  = low0;
        mainOut[rb]        = low1;
        mainOut[rb + F4_]  = low1;
        detOut[ra]         = z;
        detOut[ra + F4_]   = z;
        detOut[rb]         = z;
        detOut[rb + F4_]   = z;
        const u64 ia = (u64)(unsigned)(~t2a);
        const u64 ib = (u64)(unsigned)(~(t2a + 1));
        ins8(a0, ((u64)__float_as_uint(fabsf(e0.x - o0.x)) << 32) | ia);
        ins8(a1, ((u64)__float_as_uint(fabsf(e0.y - o0.y)) << 32) | ia);
        ins8(a2, ((u64)__float_as_uint(fabsf(e0.z - o0.z)) << 32) | ia);
        ins8(a3, ((u64)__float_as_uint(fabsf(e0.w - o0.w)) << 32) | ia);
        ins8(a0, ((u64)__float_as_uint(fabsf(e1.x - o1.x)) << 32) | ib);
        ins8(a1, ((u64)__float_as_uint(fabsf(e1.y - o1.y)) << 32) | ib);
        ins8(a2, ((u64)__float_as_uint(fabsf(e1.z - o1.z)) << 32) | ib);
        ins8(a3, ((u64)__float_as_uint(fabsf(e1.w - o1.w)) << 32) | ib);
    }

    // cand layout: (col * S + slot) * 8 + j, col = b*F + f. 64B per (col,slot).
    const size_t colBase = (size_t)b * F_ + 4 * (size_t)f4;
    u64* d0 = cand + ((colBase + 0) * S + slot) * K_;
    u64* d1 = cand + ((colBase + 1) * S + slot) * K_;
    u64* d2 = cand + ((colBase + 2) * S + slot) * K_;
    u64* d3 = cand + ((colBase + 3) * S + slot) * K_;
#pragma unroll
    for (int j = 0; j < K_; ++j) { d0[j] = a0[j]; d1[j] = a1[j]; d2[j] = a2[j]; d3[j] = a3[j]; }
}

// Phase 2: one wave per column. Coalesced candidate reads, per-lane top-8,
// 8 rounds of wave-wide u64 argmax, then lanes 0..7 scatter the winners.
__global__ __launch_bounds__(256) void haar_phase2(
    const float* __restrict__ x, const u64* __restrict__ cand,
    float* __restrict__ out, int S)
{
    const int lane = threadIdx.x & 63;
    const int wv   = threadIdx.x >> 6;
    const int col  = blockIdx.x * 4 + wv;      // b*F + f
    const int b    = col >> 9;
    const int f    = col & (F_ - 1);
    const int n    = S * K_;                   // candidates per column

    const u64* c = cand + (size_t)col * n;
    u64 a[K_];
#pragma unroll
    for (int j = 0; j < K_; ++j) a[j] = 0;
    for (int e = lane; e < n; e += 64) ins8(a, c[e]);

    u64 wkey = 0;
#pragma unroll
    for (int j = 0; j < K_; ++j) {
        u64 m = a[0];
#pragma unroll
        for (int s = 32; s > 0; s >>= 1) {
            u64 t = __shfl_xor(m, s, 64);
            m = (t > m) ? t : m;
        }
        if (a[0] == m) {            // exactly one lane (keys unique)
#pragma unroll
            for (int q = 0; q < K_ - 1; ++q) a[q] = a[q + 1];
            a[K_ - 1] = 0;
        }
        if (lane == j) wkey = m;
    }

    float* det = out + (size_t)B_ * T_ * F_;
    if (lane < K_) {
        const int t2 = (int)(~(unsigned)wkey);
        const size_t re = ((size_t)b * T_ + 2 * (size_t)t2) * F_ + f;
        const float e = x[re];
        const float o = x[re + F_];
        const float v = (e - o) * 0.5f;
        det[re]      = v;
        det[re + F_] = -v;
    }
}

extern "C" void kernel_launch(void* const* d_in, const int* in_sizes, int n_in,
                              void* d_out, int out_size, void* d_ws, size_t ws_size,
                              hipStream_t stream) {
    const float* x = (const float*)d_in[0];
    float* out = (float*)d_out;

    // Workspace: B*F*S*K u64 keys. S=256 -> 1024 phase-1 blocks (4/CU).
    int S = 256;
    while (S > 64 && (size_t)B_ * F_ * (size_t)S * K_ * sizeof(u64) > ws_size) S >>= 1;
    const int L = T2_ / S;
    u64* cand = (u64*)d_ws;

    dim3 gA(F4_ / 64, S / 4, B_);
    dim3 bA(64, 4, 1);
    hipLaunchKernelGGL(haar_phase1, gA, bA, 0, stream,
                       (const fvec4*)x, (fvec4*)out, cand, S, L);

    const int nb = (B_ * F_) / 4;   // one wave per column, 4 waves/block
    hipLaunchKernelGGL(haar_phase2, dim3(nb), dim3(256), 0, stream,
                       x, cand, out, S);
}

// Round 5
// 390.878 us; speedup vs baseline: 1.1157x; 1.1157x over previous
//
#include <hip/hip_runtime.h>
#include <math.h>

#define B_  8
#define T_  8192
#define T2_ 4096
#define F_  512
#define F4_ 128
#define K_  8

typedef unsigned long long u64;
typedef float fvec4 __attribute__((ext_vector_type(4)));

// Sorted-descending top-8 insert of packed key (abs_bits<<32)|~t2.
// Keys unique (t2 unique); ~t2 gives lower-index-first on equal abs,
// matching jax.lax.top_k.
__device__ __forceinline__ void ins8(u64 (&a)[K_], u64 k) {
    if (k <= a[K_ - 1]) return;
#pragma unroll
    for (int j = 0; j < K_; ++j) {
        u64 hi = (k > a[j]) ? k : a[j];
        u64 lo = (k > a[j]) ? a[j] : k;
        a[j] = hi;
        k = lo;
    }
}

// Phase 1: stream x once (float4 lanes over f). Write main twice-interleaved
// (NT: never re-read, keep L3 for x). Detail zeros are done by a separate
// memset. Emit per-(col,slot) top-8 candidate keys.
__global__ __launch_bounds__(256) void haar_phase1(
    const fvec4* __restrict__ x4, fvec4* __restrict__ mainOut,
    u64* __restrict__ cand, int S, int L)
{
    const int tx   = threadIdx.x;
    const int f4   = blockIdx.x * 64 + tx;            // 0..127
    const int slot = blockIdx.y * 4 + threadIdx.y;    // 0..S-1
    const int b    = blockIdx.z;
    const int t2_0 = slot * L;

    u64 a0[K_], a1[K_], a2[K_], a3[K_];
#pragma unroll
    for (int j = 0; j < K_; ++j) { a0[j] = 0; a1[j] = 0; a2[j] = 0; a3[j] = 0; }

    const size_t rowBase = (size_t)b * T_;

    for (int t = 0; t < L; ++t) {
        const int t2 = t2_0 + t;
        const size_t re = (rowBase + 2 * (size_t)t2) * F4_ + f4;  // even row
        fvec4 e = x4[re];
        fvec4 o = x4[re + F4_];
        fvec4 low = (e + o) * 0.5f;
        __builtin_nontemporal_store(low, &mainOut[re]);
        __builtin_nontemporal_store(low, &mainOut[re + F4_]);
        const u64 it = (u64)(unsigned)(~t2);
        ins8(a0, ((u64)__float_as_uint(fabsf(e.x - o.x)) << 32) | it);
        ins8(a1, ((u64)__float_as_uint(fabsf(e.y - o.y)) << 32) | it);
        ins8(a2, ((u64)__float_as_uint(fabsf(e.z - o.z)) << 32) | it);
        ins8(a3, ((u64)__float_as_uint(fabsf(e.w - o.w)) << 32) | it);
    }

    // cand layout: (col * S + slot) * 8 + j, col = b*F + f. 64B line per list.
    const size_t colBase = (size_t)b * F_ + 4 * (size_t)f4;
    u64* d0 = cand + ((colBase + 0) * S + slot) * K_;
    u64* d1 = cand + ((colBase + 1) * S + slot) * K_;
    u64* d2 = cand + ((colBase + 2) * S + slot) * K_;
    u64* d3 = cand + ((colBase + 3) * S + slot) * K_;
#pragma unroll
    for (int j = 0; j < K_; ++j) { d0[j] = a0[j]; d1[j] = a1[j]; d2[j] = a2[j]; d3[j] = a3[j]; }
}

// Phase 2: one wave per column. Coalesced candidate reads, per-lane top-8,
// 8 rounds of wave-wide u64 argmax, then lanes 0..7 scatter the winners.
__global__ __launch_bounds__(256) void haar_phase2(
    const float* __restrict__ x, const u64* __restrict__ cand,
    float* __restrict__ out, int S)
{
    const int lane = threadIdx.x & 63;
    const int wv   = threadIdx.x >> 6;
    const int col  = blockIdx.x * 4 + wv;      // b*F + f
    const int b    = col >> 9;
    const int f    = col & (F_ - 1);
    const int n    = S * K_;                   // candidates per column

    const u64* c = cand + (size_t)col * n;
    u64 a[K_];
#pragma unroll
    for (int j = 0; j < K_; ++j) a[j] = 0;
    for (int e = lane; e < n; e += 64) ins8(a, c[e]);

    u64 wkey = 0;
#pragma unroll
    for (int j = 0; j < K_; ++j) {
        u64 m = a[0];
#pragma unroll
        for (int s = 32; s > 0; s >>= 1) {
            u64 t = __shfl_xor(m, s, 64);
            m = (t > m) ? t : m;
        }
        if (a[0] == m) {            // exactly one lane (keys unique)
#pragma unroll
            for (int q = 0; q < K_ - 1; ++q) a[q] = a[q + 1];
            a[K_ - 1] = 0;
        }
        if (lane == j) wkey = m;
    }

    float* det = out + (size_t)B_ * T_ * F_;
    if (lane < K_) {
        const int t2 = (int)(~(unsigned)wkey);
        const size_t re = ((size_t)b * T_ + 2 * (size_t)t2) * F_ + f;
        const float e = x[re];
        const float o = x[re + F_];
        const float v = (e - o) * 0.5f;
        det[re]      = v;
        det[re + F_] = -v;
    }
}

extern "C" void kernel_launch(void* const* d_in, const int* in_sizes, int n_in,
                              void* d_out, int out_size, void* d_ws, size_t ws_size,
                              hipStream_t stream) {
    const float* x = (const float*)d_in[0];
    float* out = (float*)d_out;
    float* detail = out + (size_t)B_ * T_ * F_;

    // Zero the detail half at dedicated-fill bandwidth; phase2 scatters the
    // 8 nonzero rows per column afterwards (stream order guarantees safety).
    hipMemsetAsync(detail, 0, (size_t)B_ * T_ * F_ * sizeof(float), stream);

    // Workspace: B*F*S*K u64 keys. S=128: 34 MB cand, 512 phase-1 blocks.
    int S = 128;
    while (S > 32 && (size_t)B_ * F_ * (size_t)S * K_ * sizeof(u64) > ws_size) S >>= 1;
    const int L = T2_ / S;
    u64* cand = (u64*)d_ws;

    dim3 gA(F4_ / 64, S / 4, B_);
    dim3 bA(64, 4, 1);
    hipLaunchKernelGGL(haar_phase1, gA, bA, 0, stream,
                       (const fvec4*)x, (fvec4*)out, cand, S, L);

    const int nb = (B_ * F_) / 4;   // one wave per column, 4 waves/block
    hipLaunchKernelGGL(haar_phase2, dim3(nb), dim3(256), 0, stream,
                       x, cand, out, S);
}